// Round 7
// baseline (145.692 us; speedup 1.0000x reference)
//
#include <hip/hip_runtime.h>
#include <math.h>

// SineSPE R7: 1024-thread blocks (128 l-rows, q+k merged -> 256x256 output tile),
// SINGLE barrier per K-chunk (A(t) synth+write pre-barrier, MFMA(t) post-barrier;
// NA=2 A-dbuf, NB=3 B-bufs, 1-deep prefetch -- race-audited), trig from a
// precomputed bf16 table in d_ws (no transcendentals in main loop), XCD swizzle.
// Fallback: validated R6 path if ws too small for the trig table.

#define NH 8
#define NF 64
#define NK 10
#define NR 256
#define NB 4
#define NL 2048
#define KTOT 1280
#define BK 32
#define NCH (KTOT/BK)        // 40
#define NFRAG_B 16
#define WS_BPACK ((size_t)NB*NH*NCH*NFRAG_B*1024)          // 20,971,520
#define WS_TRIG  ((size_t)NH*NCH*2048*16*4)                // 41,943,040
#define WS_NEED2 (WS_BPACK + WS_TRIG)                      // 62,914,560

typedef __attribute__((ext_vector_type(8))) short short8;
typedef __attribute__((ext_vector_type(4))) float f32x4;
typedef __attribute__((ext_vector_type(4))) unsigned int u32x4;
typedef __attribute__((ext_vector_type(2))) unsigned int u32x2;

static __device__ __forceinline__ unsigned short f2b(float f) {  // fp32->bf16 RNE
    unsigned x = __float_as_uint(f);
    return (unsigned short)((x + 0x7FFFu + ((x >> 16) & 1u)) >> 16);
}
static __device__ __forceinline__ unsigned int pk2(float a, float b) {
    return (unsigned int)f2b(a) | ((unsigned int)f2b(b) << 16);
}
static __device__ __forceinline__ unsigned int cvtpk(float lo, float hi) {
    unsigned int r;
    asm("v_cvt_pk_bf16_f32 %0, %1, %2" : "=v"(r) : "v"(lo), "v"(hi));
    return r;
}
static __device__ __forceinline__ void gload_lds16(const void* g, void* l) {
    __builtin_amdgcn_global_load_lds(
        (const __attribute__((address_space(1))) unsigned int*)g,
        (__attribute__((address_space(3))) unsigned int*)l, 16, 0, 0);
}

// ---------------- prep 1: z -> bf16 frag-ordered Bpack (gains folded) --------
__global__ __launch_bounds__(256)
void spe_prep(const float* __restrict__ z, const float* __restrict__ gains,
              unsigned char* __restrict__ bpack)
{
    __shared__ float s_g[NF*NK];
    const int ch  = blockIdx.x;
    const int bh  = blockIdx.y;
    const int h   = bh & 7;
    const int tid = threadIdx.x;
    for (int i = tid; i < NF*NK; i += 256)
        s_g[i] = log1pf(expf(gains[h*NF*NK + i])) * 0.0078125f;  // softplus/128
    __syncthreads();
    const float* zb = z + (size_t)bh * KTOT * NR;
    unsigned char* dst = bpack + ((size_t)(bh*NCH + ch) * NFRAG_B) * 1024;
    #pragma unroll
    for (int it = 0; it < 4; ++it) {
        const int s  = tid + 256*it;
        const int fi = s >> 6;
        const int l  = s & 63;
        const int r  = fi*16 + (l & 15);
        const int k0 = ch*BK + (l >> 4)*8;
        u32x4 wv;
        #pragma unroll
        for (int jp = 0; jp < 4; ++jp) {
            const int ka = k0 + 2*jp, kb = ka + 1;
            const int fa = (ka*3277) >> 16; int sa = ka - fa*20; if (sa >= NK) sa -= NK;
            const int fb = (kb*3277) >> 16; int sb = kb - fb*20; if (sb >= NK) sb -= NK;
            const float va = zb[(size_t)ka*NR + r] * s_g[fa*NK + sa];
            const float vb = zb[(size_t)kb*NR + r] * s_g[fb*NK + sb];
            wv[jp] = pk2(va, vb);
        }
        *(u32x4*)(dst + (size_t)s*16) = wv;
    }
}

// ---------------- prep 2: k-phase trig table [h][40][2048][16] u32(bf16 c,s) --
__global__ __launch_bounds__(256)
void spe_trig(const float* __restrict__ freqs, unsigned int* __restrict__ trig)
{
    const int t = blockIdx.x;   // chunk 0..39
    const int h = blockIdx.y;
    const int tid = threadIdx.x;
    #pragma unroll
    for (int it = 0; it < 32; ++it) {
        const int site = tid + 256*it;     // 8192 = 2048 l x 4 j-groups
        const int l  = site >> 2;
        const int jg = site & 3;
        u32x4 wv;
        #pragma unroll
        for (int j = 0; j < 4; ++j) {
            const int kidx2 = t*16 + jg*4 + j;           // = f*10+k
            const float fv = freqs[h*640 + kidx2];
            const float fr = 0.5f / (1.0f + expf(-fv));  // rev/step
            const float x  = __builtin_amdgcn_fractf(fr * (float)l);
            wv[j] = pk2(__builtin_amdgcn_cosf(x), __builtin_amdgcn_sinf(x));
        }
        *(u32x4*)(trig + ((size_t)(h*NCH + t)*2048 + l)*16 + jg*4) = wv;
    }
}

// ---------------- main2: 1024-thr single-barrier pipeline --------------------
#define OFF2_B   0              // 3 x 16384
#define OFF2_A   49152          // 2 x 16384
#define OFF2_POS 81920          // [2][64 f][128 rq] bf16 = 32768
#define OFF2_CS  114688         // 640 x float2 (cos,sin of offset) = 5120
#define SMEM2_SZ 119808

__global__ __launch_bounds__(1024, 4)
void spe_main2(const float* __restrict__ queries, const float* __restrict__ keys,
               const float* __restrict__ offsets,
               const unsigned char* __restrict__ bpack,
               const unsigned int* __restrict__ trig,
               float* __restrict__ out)
{
    __shared__ __attribute__((aligned(16))) unsigned char smem[SMEM2_SZ];
    const int tid  = threadIdx.x;
    const int lane = tid & 63;
    const int w    = tid >> 6;            // 16 waves

    // XCD-chunked bijective swizzle (512 blocks, 512%8==0)
    const int bid = blockIdx.x;
    const int swz = (bid & 7) * 64 + (bid >> 3);
    const int l0  = (swz & 15) * 128;
    const int bh  = swz >> 4;
    const int b = bh >> 3, h = bh & 7;

    float2* ld_cs = (float2*)(smem + OFF2_CS);
    unsigned short* pos_t = (unsigned short*)(smem + OFF2_POS);

    for (int i = tid; i < NF*NK; i += 1024) {
        const float xo = __builtin_amdgcn_fractf(offsets[h*640 + i] * 0.15915494309189535f);
        ld_cs[i] = make_float2(__builtin_amdgcn_cosf(xo), __builtin_amdgcn_sinf(xo));
    }
    {   // pos tiles [qk][f][128 rows] bf16
        const int row = tid & 127;
        const int qk  = (tid >> 7) & 1;
        const int fg  = tid >> 8;          // 0..3 -> 16 f each
        const float* src = (qk ? keys : queries)
            + ((size_t)((b*NL + l0 + row)*NH + h))*NF + fg*16;
        unsigned short* pd = pos_t + qk*8192 + (fg*16)*128 + row;
        #pragma unroll
        for (int jj = 0; jj < 4; ++jj) {
            const float4 v = *(const float4*)(src + jj*4);
            pd[(jj*4+0)*128] = f2b(v.x);
            pd[(jj*4+1)*128] = f2b(v.y);
            pd[(jj*4+2)*128] = f2b(v.z);
            pd[(jj*4+3)*128] = f2b(v.w);
        }
    }
    __syncthreads();

    const unsigned char* bp = bpack + (size_t)bh * ((size_t)NCH*NFRAG_B*1024);
    const unsigned int*  tp = trig  + (size_t)h  * ((size_t)NCH*2048*16);

    const int wq = w >> 2, wn = w & 3;          // MFMA role: rows-quad / r-quad
    const int sqk  = w >> 3;                    // synth role: 0=q,1=k
    const int soct = (w >> 1) & 3;              // k-octet
    const int srq  = ((w & 1) << 6) | lane;     // row 0..127
    const unsigned short* posm = pos_t + sqk*8192;
    const int a_w = ((sqk*8 + (srq >> 4)) << 10) + ((soct*16 + (srq & 15)) << 4);
    const size_t t_off = ((size_t)(l0 + srq))*16 + soct*4;   // u32 units, + t*2048*16

    f32x4 acc[4][4];
    #pragma unroll
    for (int mi = 0; mi < 4; ++mi)
        #pragma unroll
        for (int ni = 0; ni < 4; ++ni)
            acc[mi][ni] = (f32x4){0.f, 0.f, 0.f, 0.f};

    // prologue: trig(0) + B(0)  (1 VMEM each per wave)
    u32x4 trA = *(const u32x4*)(tp + t_off);
    gload_lds16(bp + (size_t)w*1024 + (size_t)lane*16, smem + OFF2_B + (w << 10));
    u32x4 trB;

    // synth A(tt) from tr -> one conflict-free b128 into abuf
    auto synthA = [&](int tt, const u32x4& tr, int apar) {
        u32x4 av;
        #pragma unroll
        for (int p = 0; p < 4; ++p) {
            const int kidx2 = tt*16 + soct*4 + p;
            const int f = (kidx2 * 6554) >> 16;              // /10
            const float ck = __uint_as_float(tr[p] << 16);
            const float sk = __uint_as_float(tr[p] & 0xffff0000u);
            const float pv = __uint_as_float(((unsigned)posm[f*128 + srq]) << 16);
            float c, s;
            if (sqk == 0) {                                   // wave-uniform branch
                const float2 cs = ld_cs[kidx2];               // broadcast b64
                c = ck*cs.x - sk*cs.y;
                s = sk*cs.x + ck*cs.y;
            } else { c = ck; s = sk; }
            av[p] = cvtpk(c*pv, s*pv);
        }
        *(u32x4*)(smem + OFF2_A + apar*16384 + a_w) = av;
    };

    auto mfmaStep = [&](int bsel_, int apar) {
        const unsigned char* Bc = smem + OFF2_B + bsel_*16384;
        short8 bf[4];
        #pragma unroll
        for (int ni = 0; ni < 4; ++ni)
            bf[ni] = *(const short8*)(Bc + ((wn*4 + ni) << 10) + (lane << 4));
        const unsigned char* Ac = smem + OFF2_A + apar*16384;
        #pragma unroll
        for (int mi = 0; mi < 4; ++mi) {
            const short8 af = *(const short8*)(Ac + ((wq*4 + mi) << 10) + (lane << 4));
            #pragma unroll
            for (int ni = 0; ni < 4; ++ni)
                acc[mi][ni] = __builtin_amdgcn_mfma_f32_16x16x32_bf16(af, bf[ni], acc[mi][ni], 0, 0, 0);
        }
    };

    int bsel = 0;
    #pragma unroll 1
    for (int t = 0; t < NCH; t += 2) {
        // ---- sub-iter t (even): tcur=trA, prefetch t+1 -> trB ----
        {
            const int tn = t + 1;                              // t<=38 -> always valid
            const int wb = (bsel + 1 == 3) ? 0 : bsel + 1;
            trB = *(const u32x4*)(tp + (size_t)tn*2048*16 + t_off);
            gload_lds16(bp + ((size_t)tn*NFRAG_B + w)*1024 + (size_t)lane*16,
                        smem + OFF2_B + wb*16384 + (w << 10));
            asm volatile("s_waitcnt vmcnt(2)" ::: "memory");   // trig(t),B(t) landed
            __builtin_amdgcn_sched_barrier(0);
            synthA(t, trA, 0);
            asm volatile("s_waitcnt lgkmcnt(0)" ::: "memory");
            __builtin_amdgcn_sched_barrier(0);
            __builtin_amdgcn_s_barrier();                      // A(t)/B(t) visible
            mfmaStep(bsel, 0);
            bsel = wb;
        }
        // ---- sub-iter t+1 (odd): tcur=trB, prefetch t+2 -> trA ----
        {
            const int tn = (t + 2 < NCH) ? t + 2 : NCH - 1;    // clamp (dummy ok)
            const int wb = (bsel + 1 == 3) ? 0 : bsel + 1;
            trA = *(const u32x4*)(tp + (size_t)tn*2048*16 + t_off);
            gload_lds16(bp + ((size_t)tn*NFRAG_B + w)*1024 + (size_t)lane*16,
                        smem + OFF2_B + wb*16384 + (w << 10));
            asm volatile("s_waitcnt vmcnt(2)" ::: "memory");
            __builtin_amdgcn_sched_barrier(0);
            synthA(t + 1, trB, 1);
            asm volatile("s_waitcnt lgkmcnt(0)" ::: "memory");
            __builtin_amdgcn_sched_barrier(0);
            __builtin_amdgcn_s_barrier();
            mfmaStep(bsel, 1);
            bsel = wb;
        }
    }

    // epilogue: wq>>1 selects q/k output; rows (wq&1)*64 + mi*16; cols wn*64+
    const size_t qk_off = (size_t)(wq >> 1) * ((size_t)NB*NL*NH*NR);
    const int mbase = l0 + (wq & 1) * 64;
    const int row_l = (lane >> 4) * 4;
    const int col_r = lane & 15;
    #pragma unroll
    for (int mi = 0; mi < 4; ++mi) {
        const int lg = mbase + mi*16 + row_l;
        #pragma unroll
        for (int ni = 0; ni < 4; ++ni) {
            const int rg = wn*64 + ni*16 + col_r;
            const f32x4 v = acc[mi][ni];
            #pragma unroll
            for (int q = 0; q < 4; ++q)
                out[qk_off + ((size_t)((b*NL + lg + q)*NH + h))*NR + rg] = v[q];
        }
    }
}

// ---------------- fallback path: validated R6 main (2-barrier, 512-thr) ------
#define OFF_B   0
#define OFF_A   49152
#define OFF_POS 57344
#define OFF_FR  73728
#define OFF_CO  76288
#define OFF_SO  78848
#define SMEM_SZ 81408

__global__ __launch_bounds__(512, 4)
void spe_main(const float* __restrict__ queries, const float* __restrict__ keys,
              const float* __restrict__ freqs, const float* __restrict__ offsets,
              const unsigned char* __restrict__ bpack, float* __restrict__ out)
{
    __shared__ __attribute__((aligned(16))) unsigned char smem[SMEM_SZ];
    const int tid  = threadIdx.x;
    const int lane = tid & 63;
    const int w    = tid >> 6;
    const int l0   = blockIdx.x * 64;
    const int bh   = blockIdx.y;
    const int b = bh >> 3, h = bh & 7;

    float* ld_fr = (float*)(smem + OFF_FR);
    float* ld_co = (float*)(smem + OFF_CO);
    float* ld_so = (float*)(smem + OFF_SO);
    unsigned short* pos_t = (unsigned short*)(smem + OFF_POS);

    for (int i = tid; i < NF*NK; i += 512) {
        const float fv = freqs[h*NF*NK + i];
        ld_fr[i] = 0.5f / (1.0f + expf(-fv));
        const float xo = __builtin_amdgcn_fractf(offsets[h*NF*NK + i] * 0.15915494309189535f);
        ld_co[i] = __builtin_amdgcn_cosf(xo);
        ld_so[i] = __builtin_amdgcn_sinf(xo);
    }
    {
        const int r  = tid >> 2;
        const int f0 = (tid & 3) * 16;
        const int rl = r & 63;
        const float* src = (r < 64)
            ? queries + ((size_t)((b*NL + l0 + rl)*NH + h))*NF + f0
            : keys    + ((size_t)((b*NL + l0 + rl)*NH + h))*NF + f0;
        unsigned short* pdst = pos_t + ((r >> 6) << 12);
        #pragma unroll
        for (int j = 0; j < 4; ++j) {
            const float4 v = *(const float4*)(src + j*4);
            const int f = f0 + j*4;
            pdst[(f+0)*64 + rl] = f2b(v.x);
            pdst[(f+1)*64 + rl] = f2b(v.y);
            pdst[(f+2)*64 + rl] = f2b(v.z);
            pdst[(f+3)*64 + rl] = f2b(v.w);
        }
    }
    __syncthreads();

    const unsigned char* bp = bpack + (size_t)bh * ((size_t)NCH*NFRAG_B*1024);
    const int fi0 = w*2;
    gload_lds16(bp + (size_t)fi0*1024 + lane*16,               smem + OFF_B + (fi0  <<10));
    gload_lds16(bp + (size_t)(fi0+1)*1024 + lane*16,           smem + OFF_B + ((fi0+1)<<10));
    gload_lds16(bp + (size_t)(NFRAG_B + fi0)*1024 + lane*16,   smem + OFF_B + 16384 + (fi0  <<10));
    gload_lds16(bp + (size_t)(NFRAG_B + fi0+1)*1024 + lane*16, smem + OFF_B + 16384 + ((fi0+1)<<10));

    const int wm = w >> 2, wn = w & 3;
    f32x4 acc[4][4];
    #pragma unroll
    for (int mi = 0; mi < 4; ++mi)
        #pragma unroll
        for (int ni = 0; ni < 4; ++ni)
            acc[mi][ni] = (f32x4){0.f, 0.f, 0.f, 0.f};

    const int rq   = ((w & 1) << 5) | (lane & 31);
    const int oct  = w >> 1;
    const int half = lane >> 5;
    const float lf = (float)(l0 + rq);
    const unsigned short* posq = pos_t;
    const unsigned short* posk = pos_t + 4096;
    const int aw_q = OFF_A + ((rq >> 4) << 10) + ((oct*16 + (rq & 15)) << 4) + (half << 3);
    const int aw_k = aw_q + 4096;

    auto synthA = [&](int t, u32x2& q01, u32x2& k01) {
        #pragma unroll
        for (int p = 0; p < 2; ++p) {
            const int kk   = t*BK + oct*8 + half*4 + p*2;
            const int f    = (kk*3277) >> 16;
            const int srem = kk - f*20;
            const int kidx = f*NK + (srem >> 1);
            const float x  = __builtin_amdgcn_fractf(ld_fr[kidx] * lf);
            const float ck = __builtin_amdgcn_cosf(x);
            const float sk = __builtin_amdgcn_sinf(x);
            const float co = ld_co[kidx], so = ld_so[kidx];
            const float cq = ck*co - sk*so;
            const float sq = sk*co + ck*so;
            const float pq = __uint_as_float(((unsigned)posq[f*64 + rq]) << 16);
            const float pk = __uint_as_float(((unsigned)posk[f*64 + rq]) << 16);
            q01[p] = cvtpk(cq*pq, sq*pq);
            k01[p] = cvtpk(ck*pk, sk*pk);
        }
    };

    u32x2 q01, k01;
    synthA(0, q01, k01);

    int bsel  = 0;
    int bsel2 = 2;
    for (int t = 0; t < NCH; ++t) {
        if (t < NCH-1) { asm volatile("s_waitcnt vmcnt(2)" ::: "memory"); }
        else           { asm volatile("s_waitcnt vmcnt(0)" ::: "memory"); }
        __builtin_amdgcn_sched_barrier(0);
        __builtin_amdgcn_s_barrier();

        if (t + 2 < NCH) {
            unsigned char* Bn = smem + OFF_B + bsel2*16384;
            gload_lds16(bp + (size_t)((t+2)*NFRAG_B + fi0)*1024 + lane*16,
                        Bn + (fi0<<10));
            gload_lds16(bp + (size_t)((t+2)*NFRAG_B + fi0+1)*1024 + lane*16,
                        Bn + ((fi0+1)<<10));
        }

        *(u32x2*)(smem + aw_q) = q01;
        *(u32x2*)(smem + aw_k) = k01;
        asm volatile("s_waitcnt lgkmcnt(0)" ::: "memory");
        __builtin_amdgcn_sched_barrier(0);
        __builtin_amdgcn_s_barrier();

        const unsigned char* Bc = smem + OFF_B + bsel*16384;
        short8 bf[4];
        #pragma unroll
        for (int ni = 0; ni < 4; ++ni)
            bf[ni] = *(const short8*)(Bc + ((wn*4 + ni) << 10) + (lane << 4));

        if (t + 1 < NCH) synthA(t + 1, q01, k01);

        #pragma unroll
        for (int mi = 0; mi < 4; ++mi) {
            const short8 af = *(const short8*)(smem + OFF_A + ((wm*4 + mi) << 10) + (lane << 4));
            #pragma unroll
            for (int ni = 0; ni < 4; ++ni)
                acc[mi][ni] = __builtin_amdgcn_mfma_f32_16x16x32_bf16(af, bf[ni], acc[mi][ni], 0, 0, 0);
        }

        bsel  = (bsel  == 2) ? 0 : bsel  + 1;
        bsel2 = (bsel2 == 2) ? 0 : bsel2 + 1;
    }

    const size_t qk_off = (size_t)wm * ((size_t)NB*NL*NH*NR);
    const int row_l = (lane >> 4) * 4;
    const int col_r = lane & 15;
    #pragma unroll
    for (int mi = 0; mi < 4; ++mi) {
        const int lg = l0 + mi*16 + row_l;
        #pragma unroll
        for (int ni = 0; ni < 4; ++ni) {
            const int rg = wn*64 + ni*16 + col_r;
            const f32x4 v = acc[mi][ni];
            #pragma unroll
            for (int q = 0; q < 4; ++q)
                out[qk_off + ((size_t)((b*NL + lg + q)*NH + h))*NR + rg] = v[q];
        }
    }
}

extern "C" void kernel_launch(void* const* d_in, const int* in_sizes, int n_in,
                              void* d_out, int out_size, void* d_ws, size_t ws_size,
                              hipStream_t stream) {
    const float* queries = (const float*)d_in[0];
    const float* keys    = (const float*)d_in[1];
    const float* z       = (const float*)d_in[2];
    const float* freqs   = (const float*)d_in[3];
    const float* offsets = (const float*)d_in[4];
    const float* gains   = (const float*)d_in[5];
    float* out = (float*)d_out;

    unsigned char* bpack = (unsigned char*)d_ws;
    spe_prep<<<dim3(NCH, NB*NH), 256, 0, stream>>>(z, gains, bpack);

    if (ws_size >= WS_NEED2) {
        unsigned int* trig = (unsigned int*)(bpack + WS_BPACK);
        spe_trig<<<dim3(NCH, NH), 256, 0, stream>>>(freqs, trig);
        spe_main2<<<dim3(512), 1024, 0, stream>>>(queries, keys, offsets, bpack, trig, out);
    } else {
        spe_main<<<dim3(NL/64, NB*NH), 512, 0, stream>>>(queries, keys, freqs, offsets, bpack, out);
    }
}

// Round 8
// 141.193 us; speedup vs baseline: 1.0319x; 1.0319x over previous
//
#include <hip/hip_runtime.h>
#include <math.h>

// SineSPE R8: single-barrier-per-chunk pipeline. Pre-barrier: ds_write A(t) only.
// Post-barrier: issue B(t+1) DMA + trig(t+2) load (safe: all waves' reads of the
// target buffers completed before they passed the barrier), then bf/af ds_reads +
// synth(t+1) (trig table + offset rotation, no transcendentals) under 16 MFMA.
// A 2-buf (8K), B 2-buf (16K), 70.6KB LDS -> 2 blocks/CU. vmcnt(1) counted wait.

#define NH 8
#define NF 64
#define NK 10
#define NR 256
#define NB 4
#define NL 2048
#define KTOT 1280
#define BK 32
#define NCH (KTOT/BK)        // 40
#define NFRAG_B 16
#define WS_BPACK ((size_t)NB*NH*NCH*NFRAG_B*1024)          // 20,971,520
#define WS_TRIG  ((size_t)NH*NCH*2048*16*4)                // 41,943,040
#define WS_NEED2 (WS_BPACK + WS_TRIG)                      // 62,914,560

typedef __attribute__((ext_vector_type(8))) short short8;
typedef __attribute__((ext_vector_type(4))) float f32x4;
typedef __attribute__((ext_vector_type(4))) unsigned int u32x4;
typedef __attribute__((ext_vector_type(2))) unsigned int u32x2;

static __device__ __forceinline__ unsigned short f2b(float f) {  // fp32->bf16 RNE
    unsigned x = __float_as_uint(f);
    return (unsigned short)((x + 0x7FFFu + ((x >> 16) & 1u)) >> 16);
}
static __device__ __forceinline__ unsigned int pk2(float a, float b) {
    return (unsigned int)f2b(a) | ((unsigned int)f2b(b) << 16);
}
static __device__ __forceinline__ unsigned int cvtpk(float lo, float hi) {
    unsigned int r;
    asm("v_cvt_pk_bf16_f32 %0, %1, %2" : "=v"(r) : "v"(lo), "v"(hi));
    return r;
}
static __device__ __forceinline__ void gload_lds16(const void* g, void* l) {
    __builtin_amdgcn_global_load_lds(
        (const __attribute__((address_space(1))) unsigned int*)g,
        (__attribute__((address_space(3))) unsigned int*)l, 16, 0, 0);
}

// ---------------- prep 1: z -> bf16 frag-ordered Bpack (gains folded) --------
__global__ __launch_bounds__(256)
void spe_prep(const float* __restrict__ z, const float* __restrict__ gains,
              unsigned char* __restrict__ bpack)
{
    __shared__ float s_g[NF*NK];
    const int ch  = blockIdx.x;
    const int bh  = blockIdx.y;
    const int h   = bh & 7;
    const int tid = threadIdx.x;
    for (int i = tid; i < NF*NK; i += 256)
        s_g[i] = log1pf(expf(gains[h*NF*NK + i])) * 0.0078125f;  // softplus/128
    __syncthreads();
    const float* zb = z + (size_t)bh * KTOT * NR;
    unsigned char* dst = bpack + ((size_t)(bh*NCH + ch) * NFRAG_B) * 1024;
    #pragma unroll
    for (int it = 0; it < 4; ++it) {
        const int s  = tid + 256*it;
        const int fi = s >> 6;
        const int l  = s & 63;
        const int r  = fi*16 + (l & 15);
        const int k0 = ch*BK + (l >> 4)*8;
        u32x4 wv;
        #pragma unroll
        for (int jp = 0; jp < 4; ++jp) {
            const int ka = k0 + 2*jp, kb = ka + 1;
            const int fa = (ka*3277) >> 16; int sa = ka - fa*20; if (sa >= NK) sa -= NK;
            const int fb = (kb*3277) >> 16; int sb = kb - fb*20; if (sb >= NK) sb -= NK;
            const float va = zb[(size_t)ka*NR + r] * s_g[fa*NK + sa];
            const float vb = zb[(size_t)kb*NR + r] * s_g[fb*NK + sb];
            wv[jp] = pk2(va, vb);
        }
        *(u32x4*)(dst + (size_t)s*16) = wv;
    }
}

// ---------------- prep 2: k-phase trig table [h][40][2048][16] u32(bf16 c,s) --
__global__ __launch_bounds__(256)
void spe_trig(const float* __restrict__ freqs, unsigned int* __restrict__ trig)
{
    const int t = blockIdx.x;   // chunk 0..39
    const int h = blockIdx.y;
    const int tid = threadIdx.x;
    #pragma unroll
    for (int it = 0; it < 32; ++it) {
        const int site = tid + 256*it;     // 8192 = 2048 l x 4 j-groups
        const int l  = site >> 2;
        const int jg = site & 3;
        u32x4 wv;
        #pragma unroll
        for (int j = 0; j < 4; ++j) {
            const int kidx2 = t*16 + jg*4 + j;           // = f*10+k
            const float fv = freqs[h*640 + kidx2];
            const float fr = 0.5f / (1.0f + expf(-fv));  // rev/step
            const float x  = __builtin_amdgcn_fractf(fr * (float)l);
            wv[j] = pk2(__builtin_amdgcn_cosf(x), __builtin_amdgcn_sinf(x));
        }
        *(u32x4*)(trig + ((size_t)(h*NCH + t)*2048 + l)*16 + jg*4) = wv;
    }
}

// ---------------- main3: single-barrier pipeline -----------------------------
#define OFF3_B   0              // 2 x 16384
#define OFF3_A   32768          // 2 x 8192
#define OFF3_POS 49152          // [2 qk][64 f][64 rows] u16 = 16384
#define OFF3_CS  65536          // 640 float2 = 5120
#define SMEM3_SZ 70656          // <= 81920 -> 2 blocks/CU

__global__ __launch_bounds__(512, 4)
void spe_main3(const float* __restrict__ queries, const float* __restrict__ keys,
               const float* __restrict__ offsets,
               const unsigned char* __restrict__ bpack,
               const unsigned int* __restrict__ trig,
               float* __restrict__ out)
{
    __shared__ __attribute__((aligned(16))) unsigned char smem[SMEM3_SZ];
    const int tid  = threadIdx.x;
    const int lane = tid & 63;
    const int w    = tid >> 6;

    // XCD-locality decode: fb&7 = h (each XCD reuses one 5.25MB trig slice)
    const int fb = blockIdx.x;            // 0..1023
    const int h  = fb & 7;
    const int b  = (fb >> 3) & 3;
    const int l0 = (fb >> 5) * 64;
    const int bh = b*NH + h;

    float2* ld_cs = (float2*)(smem + OFF3_CS);
    unsigned short* pos_t = (unsigned short*)(smem + OFF3_POS);

    for (int i = tid; i < NF*NK; i += 512) {
        const float xo = __builtin_amdgcn_fractf(offsets[h*640 + i] * 0.15915494309189535f);
        ld_cs[i] = make_float2(__builtin_amdgcn_cosf(xo), __builtin_amdgcn_sinf(xo));
    }
    {   // pos tiles -> bf16 transposed [qk][f][64 rows]
        const int r  = tid >> 2;            // 0..127: <64 q-row, >=64 k-row
        const int f0 = (tid & 3) * 16;
        const int rl = r & 63;
        const float* src = (r < 64)
            ? queries + ((size_t)((b*NL + l0 + rl)*NH + h))*NF + f0
            : keys    + ((size_t)((b*NL + l0 + rl)*NH + h))*NF + f0;
        unsigned short* pdst = pos_t + ((r >> 6) << 12);
        #pragma unroll
        for (int j = 0; j < 4; ++j) {
            const float4 v = *(const float4*)(src + j*4);
            const int f = f0 + j*4;
            pdst[(f+0)*64 + rl] = f2b(v.x);
            pdst[(f+1)*64 + rl] = f2b(v.y);
            pdst[(f+2)*64 + rl] = f2b(v.z);
            pdst[(f+3)*64 + rl] = f2b(v.w);
        }
    }

    const unsigned char* bp = bpack + (size_t)bh * ((size_t)NCH*NFRAG_B*1024);
    const unsigned int*  tp = trig  + (size_t)h  * ((size_t)NCH*2048*16);

    const int wq   = w >> 2;              // 0=q rows, 1=k rows
    const int wn   = w & 3;               // col quarter; also synth k-octet
    const size_t tstep = (size_t)2048*16;
    const unsigned int* tbase = tp + (size_t)(l0 + lane)*16 + wn*4;
    const int a_w  = ((wq*4 + (lane >> 4)) << 10) + ((wn*16 + (lane & 15)) << 4);
    const int fi0  = w * 2;

    // prologue: trig(0), B(0), trig(1) -- FIFO: [tr0, B0a, B0b, tr1]
    u32x4 trCur = *(const u32x4*)(tbase);
    gload_lds16(bp + (size_t)fi0*1024 + lane*16,     smem + OFF3_B + (fi0  << 10));
    gload_lds16(bp + (size_t)(fi0+1)*1024 + lane*16, smem + OFF3_B + ((fi0+1) << 10));
    u32x4 trNxt = *(const u32x4*)(tbase + tstep);
    __syncthreads();   // pos/cs tables visible

    f32x4 acc[4][4];
    #pragma unroll
    for (int mi = 0; mi < 4; ++mi)
        #pragma unroll
        for (int ni = 0; ni < 4; ++ni)
            acc[mi][ni] = (f32x4){0.f, 0.f, 0.f, 0.f};

    // synth A(t): 4 kidx sites for (qk=wq, row=lane, octet=wn) -> one b128
    auto synthA = [&](int t, const u32x4 tr) -> u32x4 {
        u32x4 av;
        const int kb = t*16 + wn*4;
        #pragma unroll
        for (int p = 0; p < 4; ++p) {
            const int kidx = kb + p;
            const int f    = (kidx * 6554) >> 16;          // /10
            const float ck = __uint_as_float(tr[p] << 16);
            const float sk = __uint_as_float(tr[p] & 0xffff0000u);
            const float pv = __uint_as_float(((unsigned)pos_t[wq*4096 + f*64 + lane]) << 16);
            float c, s;
            if (wq == 0) {                                  // wave-uniform branch
                const float2 cs = ld_cs[kidx];              // broadcast read
                c = ck*cs.x - sk*cs.y;
                s = sk*cs.x + ck*cs.y;
            } else { c = ck; s = sk; }
            av[p] = cvtpk(c*pv, s*pv);
        }
        return av;
    };

    u32x4 av = synthA(0, trCur);   // consumes trig(0); leaves [B0x2, tr1] in flight

    #pragma unroll 2
    for (int t = 0; t < NCH; ++t) {
        const int par = t & 1;

        // --- pre-barrier: publish A(t); counted wait for own B(t) ---
        *(u32x4*)(smem + OFF3_A + par*8192 + a_w) = av;
        asm volatile("s_waitcnt lgkmcnt(0)" ::: "memory");
        if (t == NCH-1) { asm volatile("s_waitcnt vmcnt(0)" ::: "memory"); }
        else            { asm volatile("s_waitcnt vmcnt(1)" ::: "memory"); }
        __builtin_amdgcn_sched_barrier(0);
        __builtin_amdgcn_s_barrier();          // A(t)+B(t) visible; all reads(t-1) done
        __builtin_amdgcn_sched_barrier(0);

        // --- post-barrier: issue next-chunk B DMA + trig load (pinned) ---
        if (t + 1 < NCH) {
            unsigned char* Bn = smem + OFF3_B + ((t+1) & 1)*16384;
            gload_lds16(bp + ((size_t)(t+1)*NFRAG_B + fi0)*1024 + lane*16,
                        Bn + (fi0 << 10));
            gload_lds16(bp + ((size_t)(t+1)*NFRAG_B + fi0+1)*1024 + lane*16,
                        Bn + ((fi0+1) << 10));
        }
        u32x4 trTmp;
        if (t + 2 < NCH) trTmp = *(const u32x4*)(tbase + (size_t)(t+2)*tstep);
        __builtin_amdgcn_sched_barrier(0);     // pin issue order (vmcnt count integrity)

        // --- compute: bf/af reads, synth(t+1) under MFMA(t) ---
        const unsigned char* Bc = smem + OFF3_B + par*16384;
        short8 bf[4];
        #pragma unroll
        for (int ni = 0; ni < 4; ++ni)
            bf[ni] = *(const short8*)(Bc + ((wn*4 + ni) << 10) + (lane << 4));

        if (t + 1 < NCH) av = synthA(t + 1, trNxt);

        #pragma unroll
        for (int mi = 0; mi < 4; ++mi) {
            const short8 af = *(const short8*)(smem + OFF3_A + par*8192
                                               + ((wq*4 + mi) << 10) + (lane << 4));
            #pragma unroll
            for (int ni = 0; ni < 4; ++ni)
                acc[mi][ni] = __builtin_amdgcn_mfma_f32_16x16x32_bf16(af, bf[ni], acc[mi][ni], 0, 0, 0);
        }
        if (t + 2 < NCH) trNxt = trTmp;
    }

    // epilogue: wq selects q/k output; C/D layout col=lane&15, row=(lane>>4)*4+reg
    const size_t qk_off = (size_t)wq * ((size_t)NB*NL*NH*NR);
    const int row_l = (lane >> 4) * 4;
    const int col_r = lane & 15;
    #pragma unroll
    for (int mi = 0; mi < 4; ++mi) {
        const int lg = l0 + mi*16 + row_l;
        #pragma unroll
        for (int ni = 0; ni < 4; ++ni) {
            const int rg = wn*64 + ni*16 + col_r;
            const f32x4 v = acc[mi][ni];
            #pragma unroll
            for (int q = 0; q < 4; ++q)
                out[qk_off + ((size_t)((b*NL + lg + q)*NH + h))*NR + rg] = v[q];
        }
    }
}

// ---------------- fallback: validated R6 main (2-barrier, 512-thr) -----------
#define OFF_B   0
#define OFF_A   49152
#define OFF_POS 57344
#define OFF_FR  73728
#define OFF_CO  76288
#define OFF_SO  78848
#define SMEM_SZ 81408

__global__ __launch_bounds__(512, 4)
void spe_main(const float* __restrict__ queries, const float* __restrict__ keys,
              const float* __restrict__ freqs, const float* __restrict__ offsets,
              const unsigned char* __restrict__ bpack, float* __restrict__ out)
{
    __shared__ __attribute__((aligned(16))) unsigned char smem[SMEM_SZ];
    const int tid  = threadIdx.x;
    const int lane = tid & 63;
    const int w    = tid >> 6;
    const int l0   = blockIdx.x * 64;
    const int bh   = blockIdx.y;
    const int b = bh >> 3, h = bh & 7;

    float* ld_fr = (float*)(smem + OFF_FR);
    float* ld_co = (float*)(smem + OFF_CO);
    float* ld_so = (float*)(smem + OFF_SO);
    unsigned short* pos_t = (unsigned short*)(smem + OFF_POS);

    for (int i = tid; i < NF*NK; i += 512) {
        const float fv = freqs[h*NF*NK + i];
        ld_fr[i] = 0.5f / (1.0f + expf(-fv));
        const float xo = __builtin_amdgcn_fractf(offsets[h*NF*NK + i] * 0.15915494309189535f);
        ld_co[i] = __builtin_amdgcn_cosf(xo);
        ld_so[i] = __builtin_amdgcn_sinf(xo);
    }
    {
        const int r  = tid >> 2;
        const int f0 = (tid & 3) * 16;
        const int rl = r & 63;
        const float* src = (r < 64)
            ? queries + ((size_t)((b*NL + l0 + rl)*NH + h))*NF + f0
            : keys    + ((size_t)((b*NL + l0 + rl)*NH + h))*NF + f0;
        unsigned short* pdst = pos_t + ((r >> 6) << 12);
        #pragma unroll
        for (int j = 0; j < 4; ++j) {
            const float4 v = *(const float4*)(src + j*4);
            const int f = f0 + j*4;
            pdst[(f+0)*64 + rl] = f2b(v.x);
            pdst[(f+1)*64 + rl] = f2b(v.y);
            pdst[(f+2)*64 + rl] = f2b(v.z);
            pdst[(f+3)*64 + rl] = f2b(v.w);
        }
    }
    __syncthreads();

    const unsigned char* bp = bpack + (size_t)bh * ((size_t)NCH*NFRAG_B*1024);
    const int fi0 = w*2;
    gload_lds16(bp + (size_t)fi0*1024 + lane*16,               smem + OFF_B + (fi0  <<10));
    gload_lds16(bp + (size_t)(fi0+1)*1024 + lane*16,           smem + OFF_B + ((fi0+1)<<10));
    gload_lds16(bp + (size_t)(NFRAG_B + fi0)*1024 + lane*16,   smem + OFF_B + 16384 + (fi0  <<10));
    gload_lds16(bp + (size_t)(NFRAG_B + fi0+1)*1024 + lane*16, smem + OFF_B + 16384 + ((fi0+1)<<10));

    const int wm = w >> 2, wn = w & 3;
    f32x4 acc[4][4];
    #pragma unroll
    for (int mi = 0; mi < 4; ++mi)
        #pragma unroll
        for (int ni = 0; ni < 4; ++ni)
            acc[mi][ni] = (f32x4){0.f, 0.f, 0.f, 0.f};

    const int rq   = ((w & 1) << 5) | (lane & 31);
    const int oct  = w >> 1;
    const int half = lane >> 5;
    const float lf = (float)(l0 + rq);
    const unsigned short* posq = pos_t;
    const unsigned short* posk = pos_t + 4096;
    const int aw_q = OFF_A + ((rq >> 4) << 10) + ((oct*16 + (rq & 15)) << 4) + (half << 3);
    const int aw_k = aw_q + 4096;

    auto synthA = [&](int t, u32x2& q01, u32x2& k01) {
        #pragma unroll
        for (int p = 0; p < 2; ++p) {
            const int kk   = t*BK + oct*8 + half*4 + p*2;
            const int f    = (kk*3277) >> 16;
            const int srem = kk - f*20;
            const int kidx = f*NK + (srem >> 1);
            const float x  = __builtin_amdgcn_fractf(ld_fr[kidx] * lf);
            const float ck = __builtin_amdgcn_cosf(x);
            const float sk = __builtin_amdgcn_sinf(x);
            const float co = ld_co[kidx], so = ld_so[kidx];
            const float cq = ck*co - sk*so;
            const float sq = sk*co + ck*so;
            const float pq = __uint_as_float(((unsigned)posq[f*64 + rq]) << 16);
            const float pk = __uint_as_float(((unsigned)posk[f*64 + rq]) << 16);
            q01[p] = cvtpk(cq*pq, sq*pq);
            k01[p] = cvtpk(ck*pk, sk*pk);
        }
    };

    u32x2 q01, k01;
    synthA(0, q01, k01);

    int bsel  = 0;
    int bsel2 = 2;
    for (int t = 0; t < NCH; ++t) {
        if (t < NCH-1) { asm volatile("s_waitcnt vmcnt(2)" ::: "memory"); }
        else           { asm volatile("s_waitcnt vmcnt(0)" ::: "memory"); }
        __builtin_amdgcn_sched_barrier(0);
        __builtin_amdgcn_s_barrier();

        if (t + 2 < NCH) {
            unsigned char* Bn = smem + OFF_B + bsel2*16384;
            gload_lds16(bp + (size_t)((t+2)*NFRAG_B + fi0)*1024 + lane*16,
                        Bn + (fi0<<10));
            gload_lds16(bp + (size_t)((t+2)*NFRAG_B + fi0+1)*1024 + lane*16,
                        Bn + ((fi0+1)<<10));
        }

        *(u32x2*)(smem + aw_q) = q01;
        *(u32x2*)(smem + aw_k) = k01;
        asm volatile("s_waitcnt lgkmcnt(0)" ::: "memory");
        __builtin_amdgcn_sched_barrier(0);
        __builtin_amdgcn_s_barrier();

        const unsigned char* Bc = smem + OFF_B + bsel*16384;
        short8 bf[4];
        #pragma unroll
        for (int ni = 0; ni < 4; ++ni)
            bf[ni] = *(const short8*)(Bc + ((wn*4 + ni) << 10) + (lane << 4));

        if (t + 1 < NCH) synthA(t + 1, q01, k01);

        #pragma unroll
        for (int mi = 0; mi < 4; ++mi) {
            const short8 af = *(const short8*)(smem + OFF_A + ((wm*4 + mi) << 10) + (lane << 4));
            #pragma unroll
            for (int ni = 0; ni < 4; ++ni)
                acc[mi][ni] = __builtin_amdgcn_mfma_f32_16x16x32_bf16(af, bf[ni], acc[mi][ni], 0, 0, 0);
        }

        bsel  = (bsel  == 2) ? 0 : bsel  + 1;
        bsel2 = (bsel2 == 2) ? 0 : bsel2 + 1;
    }

    const size_t qk_off = (size_t)wm * ((size_t)NB*NL*NH*NR);
    const int row_l = (lane >> 4) * 4;
    const int col_r = lane & 15;
    #pragma unroll
    for (int mi = 0; mi < 4; ++mi) {
        const int lg = l0 + mi*16 + row_l;
        #pragma unroll
        for (int ni = 0; ni < 4; ++ni) {
            const int rg = wn*64 + ni*16 + col_r;
            const f32x4 v = acc[mi][ni];
            #pragma unroll
            for (int q = 0; q < 4; ++q)
                out[qk_off + ((size_t)((b*NL + lg + q)*NH + h))*NR + rg] = v[q];
        }
    }
}

extern "C" void kernel_launch(void* const* d_in, const int* in_sizes, int n_in,
                              void* d_out, int out_size, void* d_ws, size_t ws_size,
                              hipStream_t stream) {
    const float* queries = (const float*)d_in[0];
    const float* keys    = (const float*)d_in[1];
    const float* z       = (const float*)d_in[2];
    const float* freqs   = (const float*)d_in[3];
    const float* offsets = (const float*)d_in[4];
    const float* gains   = (const float*)d_in[5];
    float* out = (float*)d_out;

    unsigned char* bpack = (unsigned char*)d_ws;
    spe_prep<<<dim3(NCH, NB*NH), 256, 0, stream>>>(z, gains, bpack);

    if (ws_size >= WS_NEED2) {
        unsigned int* trig = (unsigned int*)(bpack + WS_BPACK);
        spe_trig<<<dim3(NCH, NH), 256, 0, stream>>>(freqs, trig);
        spe_main3<<<dim3(1024), 512, 0, stream>>>(queries, keys, offsets, bpack, trig, out);
    } else {
        spe_main<<<dim3(NL/64, NB*NH), 512, 0, stream>>>(queries, keys, freqs, offsets, bpack, out);
    }
}